// Round 5
// baseline (2647.216 us; speedup 1.0000x reference)
//
#include <hip/hip_runtime.h>
#include <cstdint>
#include <cstddef>

// GRU forward: B=64, T=1024, I=256, H=512. fp32 in/out, f16 internal compute.
//
//  1) cvt_x / cvt_w / cvt_bias: fp32 -> f16 staging
//  2) proj_gemm: P[65536][1536] = f16(xh @ Wih + bias)   (MFMA 16x16x32 f16)
//  3) gru_rec:  4 wgs per batch (256 wgs x 1024 thr, 1 wg/CU). Each thread
//     owns ONE column x ONE k-EIGHTH (64 k): weights = 96 VGPRs (3 gates x
//     32 f16x2) + ~25 working -> genuinely fits the 128-VGPR cap a
//     1024-thread block imposes. (The previous 512-thr layout demanded 232
//     VGPRs against the same 128 cap -> ~100 regs reloaded from cache EVERY
//     step = the 2.2ms floor. rocprof signature: VALUBusy 39% vs ~15%
//     modeled, VGPR_Count=128 < demand.)
//     Per-step h exchange via TAGGED 8B words (2xf16 data + 32b step tag in
//     ONE relaxed agent-scope atom) through the LLC. Single LDS-only barrier
//     per step (raw s_barrier + lgkmcnt(0), no vmcnt drain).

typedef _Float16 f16;
typedef _Float16 f16x2 __attribute__((ext_vector_type(2)));
typedef _Float16 f16x4 __attribute__((ext_vector_type(4)));
typedef _Float16 f16x8 __attribute__((ext_vector_type(8)));
typedef float    f32x4 __attribute__((ext_vector_type(4)));
typedef unsigned long long ull;

#define B_  64
#define T_  1024
#define I_  256
#define H_  512
#define N3  1536
#define WPB 256   // tagged 8B words per batch snapshot (512 h / 2 per word)

#if defined(__has_builtin)
#if __has_builtin(__builtin_amdgcn_fdot2)
#define HAS_FDOT2 1
#endif
#endif

__device__ __forceinline__ float dot2acc(f16x2 a, f16x2 b, float c) {
#ifdef HAS_FDOT2
    return __builtin_amdgcn_fdot2(a, b, c, false);
#else
    return c + (float)a.x * (float)b.x + (float)a.y * (float)b.y;
#endif
}

__device__ __forceinline__ float sigmoid_fast(float x) {
    return __builtin_amdgcn_rcpf(1.0f + __builtin_amdgcn_exp2f(-1.44269504089f * x));
}
__device__ __forceinline__ float tanh_fast(float x) {
    return 1.0f - 2.0f * __builtin_amdgcn_rcpf(1.0f + __builtin_amdgcn_exp2f(2.88539008178f * x));
}

// ---------------- converts ----------------

__global__ void cvt_x(const float* __restrict__ x, f16* __restrict__ xh, int n4) {
    int i = blockIdx.x * blockDim.x + threadIdx.x;
    if (i < n4) {
        float4 v = ((const float4*)x)[i];
        f16x4 o = { (f16)v.x, (f16)v.y, (f16)v.z, (f16)v.w };
        ((f16x4*)xh)[i] = o;
    }
}

__global__ void cvt_w(const float* __restrict__ Wir, const float* __restrict__ Wiz,
                      const float* __restrict__ Win, f16* __restrict__ WihT) {
    int id = blockIdx.x * blockDim.x + threadIdx.x;  // over 1536*256
    if (id < N3 * I_) {
        int k = id & (I_ - 1);
        int n = id >> 8;
        int g = n >> 9;
        int nn = n & (H_ - 1);
        const float* src = (g == 0) ? Wir : (g == 1) ? Wiz : Win;
        WihT[id] = (f16)src[(size_t)k * H_ + nn];
    }
}

__global__ void cvt_bias(const float* __restrict__ bir, const float* __restrict__ biz,
                         const float* __restrict__ bin, float* __restrict__ bias) {
    int i = blockIdx.x * blockDim.x + threadIdx.x;
    if (i < N3) {
        int g = i >> 9, ii = i & (H_ - 1);
        bias[i] = (g == 0) ? bir[ii] : (g == 1) ? biz[ii] : bin[ii];
    }
}

// ---------------- input projection GEMM ----------------
__global__ __launch_bounds__(512)
void proj_gemm(const f16* __restrict__ A, const f16* __restrict__ BT,
               const float* __restrict__ bias, f16* __restrict__ P) {
    __shared__ __align__(16) f16 As[128][264];
    __shared__ __align__(16) f16 Bs[128][264];

    const int tid = threadIdx.x;
    const int m0 = blockIdx.x * 128;
    const int n0 = blockIdx.y * 128;

    {
        int r = tid >> 5;
        int c = (tid & 31) * 8;
#pragma unroll
        for (int it = 0; it < 8; ++it) {
            int row = it * 16 + r;
            *(f16x8*)&As[row][c] = *(const f16x8*)(A  + (size_t)(m0 + row) * I_ + c);
            *(f16x8*)&Bs[row][c] = *(const f16x8*)(BT + (size_t)(n0 + row) * I_ + c);
        }
    }
    __syncthreads();

    const int w    = tid >> 6;
    const int lane = tid & 63;
    const int wm   = (w >> 2) * 64;
    const int wn   = (w & 3) * 32;
    const int l15  = lane & 15;
    const int quad = lane >> 4;

    f32x4 acc[4][2] = {};
#pragma unroll
    for (int kc = 0; kc < 8; ++kc) {
        int ko = kc * 32 + quad * 8;
        f16x8 a[4], b[2];
#pragma unroll
        for (int mi = 0; mi < 4; ++mi) a[mi] = *(const f16x8*)&As[wm + mi * 16 + l15][ko];
#pragma unroll
        for (int ni = 0; ni < 2; ++ni) b[ni] = *(const f16x8*)&Bs[wn + ni * 16 + l15][ko];
#pragma unroll
        for (int mi = 0; mi < 4; ++mi)
#pragma unroll
            for (int ni = 0; ni < 2; ++ni)
                acc[mi][ni] = __builtin_amdgcn_mfma_f32_16x16x32_f16(a[mi], b[ni], acc[mi][ni], 0, 0, 0);
    }

#pragma unroll
    for (int mi = 0; mi < 4; ++mi)
#pragma unroll
        for (int ni = 0; ni < 2; ++ni) {
            int col = n0 + wn + ni * 16 + l15;
            float bv = bias[col];
#pragma unroll
            for (int i = 0; i < 4; ++i) {
                int row = m0 + wm + mi * 16 + quad * 4 + i;
                P[(size_t)row * N3 + col] = (f16)(acc[mi][ni][i] + bv);
            }
        }
}

// ---------------- recurrent scan ----------------
// grid = 256 (4 wgs per batch), block = 1024 (16 waves, 1 wg/CU).
// wg (b, s): output columns [s*128, (s+1)*128), all 3 gates.
// thread t: column jloc = t>>3 (0..127); k-eighth q = t&7 (64 k-values).
//
// LDS h mirror hl[2][8][72]: parity-double-buffered, 8 k-groups of 64 f16,
// group stride 72 f16 = 144 B => group base bank = 4q (disjoint quads for the
// 8 broadcast ds_read_b128 addresses of a wave).
//
// Exchange protocol (per step, parity pb = (step+1)&1):
//  - producers (t&15==0): publish one 8B word { hi32 = step+1, lo32 = 2xf16 }
//    via relaxed agent atomic. Single atom => data+flag arrive together.
//  - q==0 lanes write own chunk straight into hl[pb]; out-store of the
//    PREVIOUS step's h at the top of the next step (ack retires under dots).
//  - pollers (t&15 in {1,2,3}, 1 word each = 192 words from 3 peers): spin
//    until tag==step+1.
//  - barrier = s_waitcnt lgkmcnt(0) + s_barrier (LDS-only; no vmcnt drain).
// Tags strictly increase and ride in the same 8B atom as the data, so stale
// reads only delay, never corrupt.
__global__ __launch_bounds__(1024)
void gru_rec(const f16* __restrict__ P,
             const float* __restrict__ Whr, const float* __restrict__ Whz,
             const float* __restrict__ Whn, const float* __restrict__ bhn,
             float* __restrict__ out,
             ull* __restrict__ hxw) {   // [2][B_][WPB] tagged words
    const int b    = blockIdx.x >> 2;
    const int s    = blockIdx.x & 3;
    const int t    = threadIdx.x;
    const int jloc = t >> 3;        // 0..127
    const int q    = t & 7;         // k-eighth
    const int jg   = s * 128 + jloc;

    __shared__ __align__(16) f16 hl[2][8][72];

    // ---- one-time weight preload into registers (96 VGPRs, fits the cap) ----
    f16x2 wr[32], wz[32], wn[32];
#pragma unroll
    for (int i = 0; i < 32; ++i) {
        int k = q * 64 + 2 * i;
        size_t o0 = (size_t)k * H_ + jg;
        size_t o1 = o0 + H_;
        wr[i] = f16x2{ (f16)Whr[o0], (f16)Whr[o1] };
        wz[i] = f16x2{ (f16)Whz[o0], (f16)Whz[o1] };
        wn[i] = f16x2{ (f16)Whn[o0], (f16)Whn[o1] };
    }
    float bh = bhn[jg];
    if (t < 288) ((float*)hl)[t] = 0.0f;   // zero hl[0] (1152 B) : h_0 = 0
    float hprev = 0.0f;
    __syncthreads();

    const f16* Pb = P + (size_t)b * T_ * N3;
    float*     ob = out + (size_t)b * T_ * H_;

    // roles within each 16-thread group (2 columns x 8 k-eighths):
    //   t&15==0        -> producer (publishes columns jloc, jloc+1)
    //   t&15 in {1..3} -> poller (one tagged peer word each; 192 total)
    const int r16     = t & 15;
    const bool poller = (r16 >= 1 && r16 <= 3);
    const int widx    = (t >> 4) * 3 + (r16 - 1);  // 0..191, valid iff poller
    const int pi      = widx >> 6;                 // 0..2
    const int pc      = pi + (pi >= s);            // peer chunk id (!= s)
    const int pw      = widx & 63;                 // word index within chunk
    const int pg      = 2 * pc + (pw >> 5);        // dest k-group in hl
    const int po      = (pw & 31) * 2;             // dest f16 offset in group

    // software-pipelined P loads
    float pr = (float)Pb[jg];
    float pz = (float)Pb[H_ + jg];
    float pn = (float)Pb[2 * H_ + jg];

#pragma unroll 1
    for (int step = 0; step < T_; ++step) {
        const int p = step & 1;

        // ---- issue-early phase: long-latency fire-and-forget VMEM ----
        if (step > 0 && q == 0)
            ob[(size_t)(step - 1) * H_ + jg] = hprev;   // previous step's h
        int np = (step + 1 < T_) ? (step + 1) : step;
        const f16* Pn = Pb + (size_t)np * N3;
        float pr2 = (float)Pn[jg];
        float pz2 = (float)Pn[H_ + jg];
        float pn2 = (float)Pn[2 * H_ + jg];

        // ---- partial dots over this thread's k-eighth (64 k-values) ----
        float sr = 0.0f, sz = 0.0f, sn = 0.0f;
#pragma unroll
        for (int c = 0; c < 4; ++c) {
            f16x8 hv[2];
#pragma unroll
            for (int u = 0; u < 2; ++u)
                hv[u] = *(const f16x8*)&hl[p][q][c * 16 + u * 8];
#pragma unroll
            for (int u = 0; u < 2; ++u) {
                const f16x2* hp = (const f16x2*)&hv[u];
#pragma unroll
                for (int v = 0; v < 4; ++v) {
                    int idx = c * 8 + u * 4 + v;
                    sr = dot2acc(wr[idx], hp[v], sr);
                    sz = dot2acc(wz[idx], hp[v], sz);
                    sn = dot2acc(wn[idx], hp[v], sn);
                }
            }
        }

        // reduce across the 8 k-eighths (lane bits 0..2, butterfly)
        sr += __shfl_xor(sr, 1, 64); sr += __shfl_xor(sr, 2, 64); sr += __shfl_xor(sr, 4, 64);
        sz += __shfl_xor(sz, 1, 64); sz += __shfl_xor(sz, 2, 64); sz += __shfl_xor(sz, 4, 64);
        sn += __shfl_xor(sn, 1, 64); sn += __shfl_xor(sn, 2, 64); sn += __shfl_xor(sn, 4, 64);

        float r = sigmoid_fast(pr + sr);
        float z = sigmoid_fast(pz + sz);
        float n = tanh_fast(pn + r * (sn + bh));
        float hnew = (1.0f - z) * n + z * hprev;
        hprev = hnew;

        if (step < T_ - 1) {
            const int pb_ = p ^ 1;
            // neighbor column's h (jloc+1 lives 8 lanes down); uniform exec
            float hnb = __shfl_down(hnew, 8, 64);
            ull* baseb = hxw + (size_t)pb_ * (B_ * WPB) + b * WPB;

            // producers: publish own pair, single tagged atom, fire-and-forget
            if (r16 == 0) {
                f16x2 pv = { (f16)hnew, (f16)hnb };
                unsigned lo = __builtin_bit_cast(unsigned int, pv);
                ull word = ((ull)(unsigned)(step + 1) << 32) | (ull)lo;
                __hip_atomic_store(baseb + s * 64 + (t >> 4), word,
                                   __ATOMIC_RELAXED, __HIP_MEMORY_SCOPE_AGENT);
            }
            // own chunk straight to LDS (columns [s*128, s*128+128) span
            // k-groups 2s and 2s+1)
            if (q == 0)
                hl[pb_][2 * s + (jloc >> 6)][jloc & 63] = (f16)hnew;
            asm volatile("" ::: "memory");
            // pollers: spin on one peer word each
            if (poller) {
                const ull* ap = baseb + pc * 64 + pw;
                const unsigned want = (unsigned)(step + 1);
                ull wv;
                do {
                    wv = __hip_atomic_load(ap, __ATOMIC_RELAXED,
                                           __HIP_MEMORY_SCOPE_AGENT);
                } while ((unsigned)(wv >> 32) != want);
                *(unsigned*)&hl[pb_][pg][po] = (unsigned)wv;
            }
            // LDS-only barrier: lgkmcnt(0) orders the ds_writes; deliberately
            // NO vmcnt drain (all store acks stay off the critical path)
            asm volatile("s_waitcnt lgkmcnt(0)" ::: "memory");
            __builtin_amdgcn_s_barrier();
            asm volatile("" ::: "memory");
        }
        pr = pr2; pz = pz2; pn = pn2;
    }
    // final row: h_{T-1}
    if (q == 0) ob[(size_t)(T_ - 1) * H_ + jg] = hprev;
}

// ---------------- launch ----------------

extern "C" void kernel_launch(void* const* d_in, const int* in_sizes, int n_in,
                              void* d_out, int out_size, void* d_ws, size_t ws_size,
                              hipStream_t stream) {
    const float* x   = (const float*)d_in[0];
    const float* Wir = (const float*)d_in[1];
    const float* Wiz = (const float*)d_in[2];
    const float* Win = (const float*)d_in[3];
    const float* bir = (const float*)d_in[4];
    const float* biz = (const float*)d_in[5];
    const float* bin = (const float*)d_in[6];
    const float* Whr = (const float*)d_in[7];
    const float* Whz = (const float*)d_in[8];
    const float* Whn = (const float*)d_in[9];
    const float* bhn = (const float*)d_in[10];
    float* out = (float*)d_out;

    char* w = (char*)d_ws;
    const size_t P_BYTES  = (size_t)B_ * T_ * N3 * sizeof(f16);   // 201,326,592
    const size_t XH_BYTES = (size_t)B_ * T_ * I_ * sizeof(f16);   //  33,554,432
    const size_t WT_BYTES = (size_t)N3 * I_ * sizeof(f16);        //     786,432
    f16*   P    = (f16*)w;
    f16*   xh   = (f16*)(w + P_BYTES);
    f16*   WihT = (f16*)(w + P_BYTES + XH_BYTES);
    float* bias = (float*)(w + P_BYTES + XH_BYTES + WT_BYTES);
    // tagged h-exchange buffer: 2*64*256*8 = 256 KB, ALIASES xh (xh is dead
    // after proj_gemm; memset below is stream-ordered after proj_gemm).
    ull*   hxw  = (ull*)(w + P_BYTES);

    {
        int n4 = (B_ * T_ * I_) / 4;
        cvt_x<<<(n4 + 255) / 256, 256, 0, stream>>>(x, xh, n4);
        int nw = N3 * I_;
        cvt_w<<<(nw + 255) / 256, 256, 0, stream>>>(Wir, Wiz, Win, WihT);
        cvt_bias<<<(N3 + 255) / 256, 256, 0, stream>>>(bir, biz, bin, bias);
    }
    {
        dim3 grid((B_ * T_) / 128, N3 / 128);
        proj_gemm<<<grid, 512, 0, stream>>>(xh, WihT, bias, P);
    }
    // zero the tag words (tags wanted are 1..1023; zero never matches)
    hipMemsetAsync(hxw, 0, (size_t)2 * B_ * WPB * sizeof(ull), stream);
    gru_rec<<<256, 1024, 0, stream>>>(P, Whr, Whz, Whn, bhn, out, hxw);
}

// Round 6
// 2356.255 us; speedup vs baseline: 1.1235x; 1.1235x over previous
//
#include <hip/hip_runtime.h>
#include <cstdint>
#include <cstddef>

// GRU forward: B=64, T=1024, I=256, H=512. fp32 in/out, f16 internal compute.
//
//  1) cvt_x / cvt_w / cvt_bias / cvt_wh: fp32 -> f16 staging (cvt_wh packs the
//     recurrent weights as [gate][col][k] so each thread's 384 weights are 48
//     contiguous f16x8 vector loads).
//  2) proj_gemm: P[65536][1536] = f16(xh @ Wih + bias)   (MFMA 16x16x32 f16)
//  3) gru_rec:  4 wgs per batch (256 wgs x 512 thr, 1 wg/CU). Weights TRULY
//     register-resident: each of the 48 f16x8 weight values is pinned via
//     asm volatile("" : "+v") after the one-time load. This forbids the
//     backend's rematerialization heuristic, which in all previous rounds
//     silently re-issued ~384 scalar weight loads per thread PER STEP to hit
//     its occupancy target (rocprof signature: VGPR_Count==128/64 == occupancy
//     budget, never == source demand; dur insensitive to every scheduling
//     change). Demand ~230 VGPR fits the 256/wave limit at 2 waves/SIMD.
//     Per-step h exchange via TAGGED 8B words (2xf16 data + 32b step tag in
//     ONE relaxed agent-scope atom) through the LLC. Single LDS-only barrier
//     per step (raw s_barrier + lgkmcnt(0), no vmcnt drain).

typedef _Float16 f16;
typedef _Float16 f16x2 __attribute__((ext_vector_type(2)));
typedef _Float16 f16x4 __attribute__((ext_vector_type(4)));
typedef _Float16 f16x8 __attribute__((ext_vector_type(8)));
typedef float    f32x4 __attribute__((ext_vector_type(4)));
typedef unsigned long long ull;

#define B_  64
#define T_  1024
#define I_  256
#define H_  512
#define N3  1536
#define WPB 256   // tagged 8B words per batch snapshot (512 h / 2 per word)

#if defined(__has_builtin)
#if __has_builtin(__builtin_amdgcn_fdot2)
#define HAS_FDOT2 1
#endif
#endif

__device__ __forceinline__ float dot2acc(f16x2 a, f16x2 b, float c) {
#ifdef HAS_FDOT2
    return __builtin_amdgcn_fdot2(a, b, c, false);
#else
    return c + (float)a.x * (float)b.x + (float)a.y * (float)b.y;
#endif
}

__device__ __forceinline__ float sigmoid_fast(float x) {
    return __builtin_amdgcn_rcpf(1.0f + __builtin_amdgcn_exp2f(-1.44269504089f * x));
}
__device__ __forceinline__ float tanh_fast(float x) {
    return 1.0f - 2.0f * __builtin_amdgcn_rcpf(1.0f + __builtin_amdgcn_exp2f(2.88539008178f * x));
}

// ---------------- converts ----------------

__global__ void cvt_x(const float* __restrict__ x, f16* __restrict__ xh, int n4) {
    int i = blockIdx.x * blockDim.x + threadIdx.x;
    if (i < n4) {
        float4 v = ((const float4*)x)[i];
        f16x4 o = { (f16)v.x, (f16)v.y, (f16)v.z, (f16)v.w };
        ((f16x4*)xh)[i] = o;
    }
}

__global__ void cvt_w(const float* __restrict__ Wir, const float* __restrict__ Wiz,
                      const float* __restrict__ Win, f16* __restrict__ WihT) {
    int id = blockIdx.x * blockDim.x + threadIdx.x;  // over 1536*256
    if (id < N3 * I_) {
        int k = id & (I_ - 1);
        int n = id >> 8;
        int g = n >> 9;
        int nn = n & (H_ - 1);
        const float* src = (g == 0) ? Wir : (g == 1) ? Wiz : Win;
        WihT[id] = (f16)src[(size_t)k * H_ + nn];
    }
}

__global__ void cvt_bias(const float* __restrict__ bir, const float* __restrict__ biz,
                         const float* __restrict__ bin, float* __restrict__ bias) {
    int i = blockIdx.x * blockDim.x + threadIdx.x;
    if (i < N3) {
        int g = i >> 9, ii = i & (H_ - 1);
        bias[i] = (g == 0) ? bir[ii] : (g == 1) ? biz[ii] : bin[ii];
    }
}

// pack recurrent weights: WhP[g][col][k] = Wh_g[k][col]  (f16, k contiguous)
__global__ void cvt_wh(const float* __restrict__ Whr, const float* __restrict__ Whz,
                       const float* __restrict__ Whn, f16* __restrict__ WhP) {
    int id = blockIdx.x * blockDim.x + threadIdx.x;  // over 3*512*512
    if (id < 3 * H_ * H_) {
        int k   = id & (H_ - 1);
        int col = (id >> 9) & (H_ - 1);
        int g   = id >> 18;
        const float* src = (g == 0) ? Whr : (g == 1) ? Whz : Whn;
        WhP[id] = (f16)src[(size_t)k * H_ + col];
    }
}

// ---------------- input projection GEMM ----------------
__global__ __launch_bounds__(512)
void proj_gemm(const f16* __restrict__ A, const f16* __restrict__ BT,
               const float* __restrict__ bias, f16* __restrict__ P) {
    __shared__ __align__(16) f16 As[128][264];
    __shared__ __align__(16) f16 Bs[128][264];

    const int tid = threadIdx.x;
    const int m0 = blockIdx.x * 128;
    const int n0 = blockIdx.y * 128;

    {
        int r = tid >> 5;
        int c = (tid & 31) * 8;
#pragma unroll
        for (int it = 0; it < 8; ++it) {
            int row = it * 16 + r;
            *(f16x8*)&As[row][c] = *(const f16x8*)(A  + (size_t)(m0 + row) * I_ + c);
            *(f16x8*)&Bs[row][c] = *(const f16x8*)(BT + (size_t)(n0 + row) * I_ + c);
        }
    }
    __syncthreads();

    const int w    = tid >> 6;
    const int lane = tid & 63;
    const int wm   = (w >> 2) * 64;
    const int wn   = (w & 3) * 32;
    const int l15  = lane & 15;
    const int quad = lane >> 4;

    f32x4 acc[4][2] = {};
#pragma unroll
    for (int kc = 0; kc < 8; ++kc) {
        int ko = kc * 32 + quad * 8;
        f16x8 a[4], b[2];
#pragma unroll
        for (int mi = 0; mi < 4; ++mi) a[mi] = *(const f16x8*)&As[wm + mi * 16 + l15][ko];
#pragma unroll
        for (int ni = 0; ni < 2; ++ni) b[ni] = *(const f16x8*)&Bs[wn + ni * 16 + l15][ko];
#pragma unroll
        for (int mi = 0; mi < 4; ++mi)
#pragma unroll
            for (int ni = 0; ni < 2; ++ni)
                acc[mi][ni] = __builtin_amdgcn_mfma_f32_16x16x32_f16(a[mi], b[ni], acc[mi][ni], 0, 0, 0);
    }

#pragma unroll
    for (int mi = 0; mi < 4; ++mi)
#pragma unroll
        for (int ni = 0; ni < 2; ++ni) {
            int col = n0 + wn + ni * 16 + l15;
            float bv = bias[col];
#pragma unroll
            for (int i = 0; i < 4; ++i) {
                int row = m0 + wm + mi * 16 + quad * 4 + i;
                P[(size_t)row * N3 + col] = (f16)(acc[mi][ni][i] + bv);
            }
        }
}

// ---------------- recurrent scan ----------------
// grid = 256 (4 wgs per batch), block = 512 (8 waves, 1 wg/CU).
// wg (b, s): output columns [s*128, (s+1)*128), all 3 gates.
// thread t: column j = s*128 + (t>>2); k-quarter q = t&3 (128 k-values).
//
// Exchange protocol (per step, parity pb = (step+1)&1):
//  - producers (t&7==0): publish one 8B word { hi32 = step+1, lo32 = 2xf16 }
//    via relaxed agent atomic. Single atom => data+flag arrive together.
//  - q==0 lanes write own chunk straight into hl[pb] (LDS); out-store of the
//    PREVIOUS step's h at the top of the next step (ack retires under dots).
//  - pollers (t&7 in {1,2,3}, 1 word/lane): spin until tag==step+1.
//  - barrier = s_waitcnt lgkmcnt(0) + s_barrier (LDS-only; no vmcnt drain).
// Tags strictly increase and ride in the same 8B atom as the data, so stale
// reads only delay, never corrupt.
__global__ __launch_bounds__(512, 1)
void gru_rec(const f16* __restrict__ P,
             const f16* __restrict__ WhP, const float* __restrict__ bhn,
             float* __restrict__ out,
             ull* __restrict__ hxw) {   // [2][B_][WPB] tagged words
    const int b    = blockIdx.x >> 2;
    const int s    = blockIdx.x & 3;
    const int t    = threadIdx.x;
    const int jloc = t >> 2;        // 0..127
    const int q    = t & 3;         // k-quarter
    const int jg   = s * 128 + jloc;

    // hl: parity-double-buffered h, 4 padded chunks (chunk stride 136 f16 =
    // 272 B) so the four q-groups' 16B reads land on disjoint bank quads.
    __shared__ __align__(16) f16 hl[2][4][136];

    // ---- one-time weight preload: 48 x f16x8 = 192 VGPRs, then PINNED so the
    //      backend cannot rematerialize the loads inside the step loop ----
    f16x8 w8[3][16];
    {
        const f16* wpB = WhP + (size_t)jg * H_ + q * 128;
#pragma unroll
        for (int g = 0; g < 3; ++g) {
            const f16* wp = wpB + (size_t)g * H_ * H_;
#pragma unroll
            for (int i = 0; i < 16; ++i)
                w8[g][i] = *(const f16x8*)(wp + i * 8);
        }
    }
#pragma unroll
    for (int g = 0; g < 3; ++g)
#pragma unroll
        for (int i = 0; i < 16; ++i)
            asm volatile("" : "+v"(w8[g][i]));   // remat barrier: keep in VGPRs

    float bh = bhn[jg];
    if (t < 272) ((float*)hl)[t] = 0.0f;   // zero hl[0] (1088 B) : h_0 = 0
    float hprev = 0.0f;
    __syncthreads();

    const f16* Pb = P + (size_t)b * T_ * N3;
    float*     ob = out + (size_t)b * T_ * H_;

    // poller role: t&7 in {1,2,3} -> flat word index 0..191 -> (peer chunk, word)
    const int r8      = t & 7;
    const bool poller = (r8 >= 1 && r8 <= 3);
    const int widx    = (t >> 3) * 3 + (r8 - 1);   // valid iff poller
    const int pi      = widx >> 6;                 // 0..2
    const int pc      = pi + (pi >= s);            // peer chunk id (!= s)
    const int pw      = widx & 63;                 // word index within chunk

    // software-pipelined P loads
    float pr = (float)Pb[jg];
    float pz = (float)Pb[H_ + jg];
    float pn = (float)Pb[2 * H_ + jg];

#pragma unroll 1
    for (int step = 0; step < T_; ++step) {
        const int p = step & 1;

        // ---- issue-early phase: all long-latency fire-and-forget VMEM ----
        if (step > 0 && q == 0)
            ob[(size_t)(step - 1) * H_ + jg] = hprev;   // previous step's h
        int np = (step + 1 < T_) ? (step + 1) : step;
        const f16* Pn = Pb + (size_t)np * N3;
        float pr2 = (float)Pn[jg];
        float pz2 = (float)Pn[H_ + jg];
        float pn2 = (float)Pn[2 * H_ + jg];

        // ---- partial dots over this thread's k-quarter (128 k-values) ----
        float sr = 0.0f, sz = 0.0f, sn = 0.0f;
#pragma unroll
        for (int c = 0; c < 4; ++c) {
            f16x8 hv[4];
#pragma unroll
            for (int u = 0; u < 4; ++u)
                hv[u] = *(const f16x8*)&hl[p][q][c * 32 + u * 8];
#pragma unroll
            for (int u = 0; u < 4; ++u) {
                const f16x2* hp  = (const f16x2*)&hv[u];
                const f16x2* wrp = (const f16x2*)&w8[0][c * 4 + u];
                const f16x2* wzp = (const f16x2*)&w8[1][c * 4 + u];
                const f16x2* wnp = (const f16x2*)&w8[2][c * 4 + u];
#pragma unroll
                for (int v = 0; v < 4; ++v) {
                    sr = dot2acc(wrp[v], hp[v], sr);
                    sz = dot2acc(wzp[v], hp[v], sz);
                    sn = dot2acc(wnp[v], hp[v], sn);
                }
            }
        }

        // reduce across the 4 k-quarters (lanes 4j..4j+3, butterfly)
        sr += __shfl_xor(sr, 1, 64); sr += __shfl_xor(sr, 2, 64);
        sz += __shfl_xor(sz, 1, 64); sz += __shfl_xor(sz, 2, 64);
        sn += __shfl_xor(sn, 1, 64); sn += __shfl_xor(sn, 2, 64);

        float r = sigmoid_fast(pr + sr);
        float z = sigmoid_fast(pz + sz);
        float n = tanh_fast(pn + r * (sn + bh));
        float hnew = (1.0f - z) * n + z * hprev;
        hprev = hnew;

        if (step < T_ - 1) {
            const int pb_ = p ^ 1;
            // neighbor column's h (jloc+1 lives at lane+4); uniform exec
            float hnb = __shfl_down(hnew, 4, 64);
            ull* baseb = hxw + (size_t)pb_ * (B_ * WPB) + b * WPB;

            // producers: publish own pair, single tagged atom, fire-and-forget
            if (r8 == 0) {
                f16x2 pv = { (f16)hnew, (f16)hnb };
                unsigned lo = __builtin_bit_cast(unsigned int, pv);
                ull word = ((ull)(unsigned)(step + 1) << 32) | (ull)lo;
                __hip_atomic_store(baseb + s * 64 + (t >> 3), word,
                                   __ATOMIC_RELAXED, __HIP_MEMORY_SCOPE_AGENT);
            }
            // own chunk straight to LDS (no global round-trip)
            if (q == 0) hl[pb_][s][jloc] = (f16)hnew;
            asm volatile("" ::: "memory");
            // pollers: spin on one peer word each
            if (poller) {
                const ull* ap = baseb + pc * 64 + pw;
                const unsigned want = (unsigned)(step + 1);
                ull wv;
                do {
                    wv = __hip_atomic_load(ap, __ATOMIC_RELAXED,
                                           __HIP_MEMORY_SCOPE_AGENT);
                } while ((unsigned)(wv >> 32) != want);
                *(unsigned*)&hl[pb_][pc][pw * 2] = (unsigned)wv;
            }
            // LDS-only barrier: lgkmcnt(0) orders the ds_writes; deliberately
            // NO vmcnt drain (all store acks stay off the critical path)
            asm volatile("s_waitcnt lgkmcnt(0)" ::: "memory");
            __builtin_amdgcn_s_barrier();
            asm volatile("" ::: "memory");
        }
        pr = pr2; pz = pz2; pn = pn2;
    }
    // final row: h_{T-1}
    if (q == 0) ob[(size_t)(T_ - 1) * H_ + jg] = hprev;
}

// ---------------- launch ----------------

extern "C" void kernel_launch(void* const* d_in, const int* in_sizes, int n_in,
                              void* d_out, int out_size, void* d_ws, size_t ws_size,
                              hipStream_t stream) {
    const float* x   = (const float*)d_in[0];
    const float* Wir = (const float*)d_in[1];
    const float* Wiz = (const float*)d_in[2];
    const float* Win = (const float*)d_in[3];
    const float* bir = (const float*)d_in[4];
    const float* biz = (const float*)d_in[5];
    const float* bin = (const float*)d_in[6];
    const float* Whr = (const float*)d_in[7];
    const float* Whz = (const float*)d_in[8];
    const float* Whn = (const float*)d_in[9];
    const float* bhn = (const float*)d_in[10];
    float* out = (float*)d_out;

    char* w = (char*)d_ws;
    const size_t P_BYTES  = (size_t)B_ * T_ * N3 * sizeof(f16);   // 201,326,592
    const size_t XH_BYTES = (size_t)B_ * T_ * I_ * sizeof(f16);   //  33,554,432
    const size_t WT_BYTES = (size_t)N3 * I_ * sizeof(f16);        //     786,432
    const size_t BI_BYTES = (size_t)N3 * sizeof(float);           //       6,144
    f16*   P    = (f16*)w;
    f16*   xh   = (f16*)(w + P_BYTES);
    f16*   WihT = (f16*)(w + P_BYTES + XH_BYTES);
    float* bias = (float*)(w + P_BYTES + XH_BYTES + WT_BYTES);
    f16*   WhP  = (f16*)(w + P_BYTES + XH_BYTES + WT_BYTES + BI_BYTES); // 1.5 MB
    // tagged h-exchange buffer: 2*64*256*8 = 256 KB, ALIASES xh (xh is dead
    // after proj_gemm; memset below is stream-ordered after proj_gemm).
    ull*   hxw  = (ull*)(w + P_BYTES);

    {
        int n4 = (B_ * T_ * I_) / 4;
        cvt_x<<<(n4 + 255) / 256, 256, 0, stream>>>(x, xh, n4);
        int nw = N3 * I_;
        cvt_w<<<(nw + 255) / 256, 256, 0, stream>>>(Wir, Wiz, Win, WihT);
        cvt_bias<<<(N3 + 255) / 256, 256, 0, stream>>>(bir, biz, bin, bias);
        int nwh = 3 * H_ * H_;
        cvt_wh<<<(nwh + 255) / 256, 256, 0, stream>>>(Whr, Whz, Whn, WhP);
    }
    {
        dim3 grid((B_ * T_) / 128, N3 / 128);
        proj_gemm<<<grid, 512, 0, stream>>>(xh, WihT, bias, P);
    }
    // zero the tag words (tags wanted are 1..1023; zero never matches)
    hipMemsetAsync(hxw, 0, (size_t)2 * B_ * WPB * sizeof(ull), stream);
    gru_rec<<<256, 512, 0, stream>>>(P, WhP, bhn, out, hxw);
}